// Round 2
// baseline (848.440 us; speedup 1.0000x reference)
//
#include <hip/hip_runtime.h>
#include <math.h>

// Problem constants
#define NROWS  131072            // B*T
#define OUT_N  33554432          // NROWS*256
#define TM     64                // rows per block in main kernel
typedef unsigned int uint;

// ---- workspace layout (bytes) ----
#define WS_DIFF   0                       // double
#define WS_ENT    8                       // double
#define C32_OFF   64                      // float [512]   |ehat_j|^2, np fp32 semantics
#define EHAT_OFF  4096                    // float [512*256]
#define EHATT_OFF (EHAT_OFF + 524288)     // float [256*512]
#define XX_OFF    (EHATT_OFF + 524288)    // float [131072] |x_n|^2, np fp32 semantics

__device__ __forceinline__ float f4c(const float4 v, int c) {
    return c == 0 ? v.x : (c == 1 ? v.y : (c == 2 ? v.z : v.w));
}

// ---------------------------------------------------------------------------
// numpy pairwise_sum emulation for n=128 contiguous f32 (AVX512 build):
// 8 vector accumulators of 16 lanes: r_j[l] = y[j*16+l] (one load each, n=128);
// combine ((r0+r1)+(r2+r3))+((r4+r5)+(r6+r7)) lane-wise, then
// _mm512_reduce_add_ps tree: stride 8, 4, then (u0+u2)+(u1+u3).
// y_d = fl32(p[d]*p[d]) — squares rounded BEFORE summation (separate np temp).
// ---------------------------------------------------------------------------
__device__ __forceinline__ float np_b128_sq(const float* p) {
    float L[16];
    #pragma unroll
    for (int l = 0; l < 16; ++l) {
        float y[8];
        #pragma unroll
        for (int j = 0; j < 8; ++j) { float v = p[j * 16 + l]; y[j] = __fmul_rn(v, v); }
        L[l] = __fadd_rn(__fadd_rn(__fadd_rn(y[0], y[1]), __fadd_rn(y[2], y[3])),
                         __fadd_rn(__fadd_rn(y[4], y[5]), __fadd_rn(y[6], y[7])));
    }
    float w[8];
    #pragma unroll
    for (int l = 0; l < 8; ++l) w[l] = __fadd_rn(L[l], L[l + 8]);
    float u[4];
    #pragma unroll
    for (int l = 0; l < 4; ++l) u[l] = __fadd_rn(w[l], w[l + 4]);
    return __fadd_rn(__fadd_rn(u[0], u[2]), __fadd_rn(u[1], u[3]));
}

// same tree but y_d = fl32( fl32(p[d]/nrm)^2 )  (normalized-codebook squares)
__device__ __forceinline__ float np_b128_nsq(const float* p, float nrm) {
    float L[16];
    #pragma unroll
    for (int l = 0; l < 16; ++l) {
        float y[8];
        #pragma unroll
        for (int j = 0; j < 8; ++j) {
            float v = __fdiv_rn(p[j * 16 + l], nrm);
            y[j] = __fmul_rn(v, v);
        }
        L[l] = __fadd_rn(__fadd_rn(__fadd_rn(y[0], y[1]), __fadd_rn(y[2], y[3])),
                         __fadd_rn(__fadd_rn(y[4], y[5]), __fadd_rn(y[6], y[7])));
    }
    float w[8];
    #pragma unroll
    for (int l = 0; l < 8; ++l) w[l] = __fadd_rn(L[l], L[l + 8]);
    float u[4];
    #pragma unroll
    for (int l = 0; l < 4; ++l) u[l] = __fadd_rn(w[l], w[l + 4]);
    return __fadd_rn(__fadd_rn(u[0], u[2]), __fadd_rn(u[1], u[3]));
}

// ---------------------------------------------------------------------------
// Kernel 1: per-codebook-row e: norm32 (np semantics), ehat32 = EMB/norm32,
// c32 = np-sum(ehat^2). Writes Ehat row-major + EhatT transposed. grid 2x256.
// ---------------------------------------------------------------------------
__global__ __launch_bounds__(256) void vq_prep(
    const float* __restrict__ EMB, float* __restrict__ Ehat,
    float* __restrict__ EhatT, float* __restrict__ c32,
    double* __restrict__ diff_sum)
{
    const int e = blockIdx.x * 256 + threadIdx.x;   // 0..511
    const float* row = EMB + e * 256;
    float ss  = __fadd_rn(np_b128_sq(row), np_b128_sq(row + 128));
    float nrm = __fsqrt_rn(ss);                     // np.sqrt f32, correctly rounded
    for (int d = 0; d < 256; ++d) {
        float eh = __fdiv_rn(row[d], nrm);          // np divide, correctly rounded
        Ehat[e * 256 + d]  = eh;
        EhatT[d * 512 + e] = eh;
    }
    c32[e] = __fadd_rn(np_b128_nsq(row, nrm), np_b128_nsq(row + 128, nrm));
    if (e == 0) *diff_sum = 0.0;
}

// ---------------------------------------------------------------------------
// Kernel 2: xx32[n] = np-pairwise-f32 sum of x_n^2. 16 rows/block via LDS.
// grid 8192 x 256.
// ---------------------------------------------------------------------------
__global__ __launch_bounds__(256) void vq_xx(const float* __restrict__ X,
                                             float* __restrict__ xx32)
{
    __shared__ float xs[16 * 256];
    const int tid = threadIdx.x;
    const float4* Xv = (const float4*)X;
    float4* xs4 = (float4*)xs;
    const size_t base = (size_t)blockIdx.x * 1024;
    #pragma unroll
    for (int p = 0; p < 4; ++p) xs4[p * 256 + tid] = Xv[base + p * 256 + tid];
    __syncthreads();
    if (tid < 16) {
        const float* row = xs + tid * 256;
        xx32[blockIdx.x * 16 + tid] =
            __fadd_rn(np_b128_sq(row), np_b128_sq(row + 128));
    }
}

// ---------------------------------------------------------------------------
// Kernel 3: fused GEMM (exact sequential-k fp32 FMA chain, emulating BLAS) +
// np-exact dist32 + first-min argmin + gather/out/diff.
// grid 2048 x 256; block = 64 rows x 512 codes.
// ---------------------------------------------------------------------------
__global__ __launch_bounds__(256) void vq_main(
    const float* __restrict__ X, const float* __restrict__ EhatT,
    const float* __restrict__ Ehat, const float* __restrict__ XX,
    const float* __restrict__ C32, float* __restrict__ out,
    float* __restrict__ ind_out, double* __restrict__ diff_sum)
{
    __shared__ float4 ET4[64 * 16];     // 64 k-rows x 64 j (16 KB), k-major
    __shared__ int    indsh[TM];
    __shared__ double dred[4];

    const int tid = threadIdx.x;
    const int tj  = tid & 15;
    const int tmG = tid >> 4;
    const int m0  = blockIdx.x * TM;

    const float4* xr0 = (const float4*)(X + (size_t)(m0 + tmG * 4 + 0) * 256);
    const float4* xr1 = (const float4*)(X + (size_t)(m0 + tmG * 4 + 1) * 256);
    const float4* xr2 = (const float4*)(X + (size_t)(m0 + tmG * 4 + 2) * 256);
    const float4* xr3 = (const float4*)(X + (size_t)(m0 + tmG * 4 + 3) * 256);
    const float4* Ev  = (const float4*)EhatT;

    float xxv[4];
    #pragma unroll
    for (int i = 0; i < 4; ++i) xxv[i] = XX[m0 + tmG * 4 + i];

    float bd[4]; int bj[4];
    #pragma unroll
    for (int i = 0; i < 4; ++i) { bd[i] = 3.0e38f; bj[i] = 0; }

    for (int jc = 0; jc < 8; ++jc) {
        float acc[4][4];
        #pragma unroll
        for (int i = 0; i < 4; ++i)
            #pragma unroll
            for (int c = 0; c < 4; ++c) acc[i][c] = 0.0f;

        for (int kc = 0; kc < 4; ++kc) {
            __syncthreads();
            #pragma unroll
            for (int p = 0; p < 4; ++p) {
                int L  = p * 256 + tid;
                int kk = L >> 4;
                int j4 = L & 15;
                ET4[kk * 16 + j4] = Ev[(size_t)(kc * 64 + kk) * 128 + jc * 16 + j4];
            }
            __syncthreads();
            // d ascends (kc,k4,c4): each acc[i][c] is ONE sequential fp32 FMA
            // chain over d=0..255 from 0 — bit-matching BLAS sgemm rank-1 order.
            #pragma unroll 4
            for (int k4 = 0; k4 < 16; ++k4) {
                const int f4i = kc * 16 + k4;
                float4 a0 = xr0[f4i];
                float4 a1 = xr1[f4i];
                float4 a2 = xr2[f4i];
                float4 a3 = xr3[f4i];
                #pragma unroll
                for (int c4 = 0; c4 < 4; ++c4) {
                    float4 b = ET4[(k4 * 4 + c4) * 16 + tj];
                    float av;
                    av = f4c(a0, c4);
                    acc[0][0] = fmaf(av, b.x, acc[0][0]);
                    acc[0][1] = fmaf(av, b.y, acc[0][1]);
                    acc[0][2] = fmaf(av, b.z, acc[0][2]);
                    acc[0][3] = fmaf(av, b.w, acc[0][3]);
                    av = f4c(a1, c4);
                    acc[1][0] = fmaf(av, b.x, acc[1][0]);
                    acc[1][1] = fmaf(av, b.y, acc[1][1]);
                    acc[1][2] = fmaf(av, b.z, acc[1][2]);
                    acc[1][3] = fmaf(av, b.w, acc[1][3]);
                    av = f4c(a2, c4);
                    acc[2][0] = fmaf(av, b.x, acc[2][0]);
                    acc[2][1] = fmaf(av, b.y, acc[2][1]);
                    acc[2][2] = fmaf(av, b.z, acc[2][2]);
                    acc[2][3] = fmaf(av, b.w, acc[2][3]);
                    av = f4c(a3, c4);
                    acc[3][0] = fmaf(av, b.x, acc[3][0]);
                    acc[3][1] = fmaf(av, b.y, acc[3][1]);
                    acc[3][2] = fmaf(av, b.z, acc[3][2]);
                    acc[3][3] = fmaf(av, b.w, acc[3][3]);
                }
            }
        }
        // np-exact dist32 = fl32( fl32(xx - 2g) + c_j ); argmin, first-min ties
        float cj[4];
        #pragma unroll
        for (int c = 0; c < 4; ++c) cj[c] = C32[jc * 64 + tj * 4 + c];
        #pragma unroll
        for (int i = 0; i < 4; ++i)
            #pragma unroll
            for (int c = 0; c < 4; ++c) {
                float g2  = __fmul_rn(2.0f, acc[i][c]);        // exact (x2)
                float d32 = __fadd_rn(__fsub_rn(xxv[i], g2), cj[c]);
                int   j   = jc * 64 + tj * 4 + c;              // ascending
                if (d32 < bd[i]) { bd[i] = d32; bj[i] = j; }   // keep first min
            }
    }

    // merge across the 16 tj lanes: min dist, ties -> smaller index
    #pragma unroll
    for (int off = 1; off <= 8; off <<= 1) {
        #pragma unroll
        for (int i = 0; i < 4; ++i) {
            float od = __shfl_xor(bd[i], off, 64);
            int   oj = __shfl_xor(bj[i], off, 64);
            if (od < bd[i] || (od == bd[i] && oj < bj[i])) { bd[i] = od; bj[i] = oj; }
        }
    }
    if ((tid & 15) == 0) {
        #pragma unroll
        for (int i = 0; i < 4; ++i) indsh[tmG * 4 + i] = bj[i];
    }
    __syncthreads();

    // epilogue: gather + out + diff
    double dacc = 0.0;
    const int d = tid;
    for (int r = 0; r < TM; ++r) {
        int idx = indsh[r];
        float q = Ehat[idx * 256 + d];
        float x = X[(size_t)(m0 + r) * 256 + d];
        out[(size_t)(m0 + r) * 256 + d] = q;
        float dv = q - x;
        dacc += (double)dv * (double)dv;
    }
    if (tid < TM) ind_out[m0 + tid] = (float)indsh[tid];

    #pragma unroll
    for (int off = 32; off; off >>= 1) dacc += __shfl_down(dacc, off, 64);
    if ((tid & 63) == 0) dred[tid >> 6] = dacc;
    __syncthreads();
    if (tid == 0) atomicAdd(diff_sum, dred[0] + dred[1] + dred[2] + dred[3]);
}

// ---------------------------------------------------------------------------
// Kernel 4: entropy = 2E*sum|ehat|^2 - 2|sum ehat|^2 (f64; loss is lax-graded)
// ---------------------------------------------------------------------------
__global__ __launch_bounds__(256) void vq_entropy(const float* __restrict__ Ehat,
                                                  const float* __restrict__ c32,
                                                  double* __restrict__ ent)
{
    __shared__ double red[256];
    const int tid = threadIdx.x;
    double sd = 0.0;
    for (int e = 0; e < 512; ++e) sd += (double)Ehat[e * 256 + tid];
    red[tid] = sd * sd;
    __syncthreads();
    for (int st = 128; st; st >>= 1) {
        if (tid < st) red[tid] += red[tid + st];
        __syncthreads();
    }
    double s2 = red[0];
    __syncthreads();
    red[tid] = (double)c32[tid] + (double)c32[tid + 256];
    __syncthreads();
    for (int st = 128; st; st >>= 1) {
        if (tid < st) red[tid] += red[tid + st];
        __syncthreads();
    }
    if (tid == 0) *ent = 2.0 * 512.0 * red[0] - 2.0 * s2;
}

// ---------------------------------------------------------------------------
// Kernel 5: loss = diff/(N*D) - entropy/E^2
// ---------------------------------------------------------------------------
__global__ void vq_finalize(const double* __restrict__ diff_sum,
                            const double* __restrict__ ent,
                            float* __restrict__ loss_out)
{
    if (threadIdx.x == 0 && blockIdx.x == 0) {
        *loss_out = (float)((*diff_sum) * (1.0 / (double)OUT_N)
                            - (*ent) * (1.0 / (512.0 * 512.0)));
    }
}

// ---------------------------------------------------------------------------
extern "C" void kernel_launch(void* const* d_in, const int* in_sizes, int n_in,
                              void* d_out, int out_size, void* d_ws, size_t ws_size,
                              hipStream_t stream)
{
    const float* X   = (const float*)d_in[0];   // [32,4096,256] fp32
    const float* EMB = (const float*)d_in[1];   // [512,256] fp32

    float* out      = (float*)d_out;            // [N,D]
    float* loss_out = out + OUT_N;              // scalar
    float* ind_out  = out + OUT_N + 1;          // [N] (float-encoded indices)

    char* ws = (char*)d_ws;
    double* diff_sum = (double*)(ws + WS_DIFF);
    double* ent      = (double*)(ws + WS_ENT);
    float*  c32      = (float*) (ws + C32_OFF);
    float*  Ehat     = (float*) (ws + EHAT_OFF);
    float*  EhatT    = (float*) (ws + EHATT_OFF);
    float*  xx32     = (float*) (ws + XX_OFF);

    vq_prep<<<2, 256, 0, stream>>>(EMB, Ehat, EhatT, c32, diff_sum);
    vq_xx<<<8192, 256, 0, stream>>>(X, xx32);
    vq_main<<<2048, 256, 0, stream>>>(X, EhatT, Ehat, xx32, c32, out, ind_out, diff_sum);
    vq_entropy<<<1, 256, 0, stream>>>(Ehat, c32, ent);
    vq_finalize<<<1, 64, 0, stream>>>(diff_sum, ent, loss_out);
}

// Round 3
// 682.784 us; speedup vs baseline: 1.2426x; 1.2426x over previous
//
#include <hip/hip_runtime.h>
#include <math.h>

// Problem constants
#define NROWS  131072            // B*T
#define OUT_N  33554432          // NROWS*256
typedef unsigned int uint;

// ---- workspace layout (bytes) ----
#define WS_DIFF   0                       // double
#define C32_OFF   64                      // float [512]   |ehat_j|^2, np fp32 semantics
#define EHAT_OFF  4096                    // float [512*256]
#define EHATT_OFF (EHAT_OFF + 524288)     // float [256*512]

__device__ __forceinline__ float f4c(const float4 v, int c) {
    return c == 0 ? v.x : (c == 1 ? v.y : (c == 2 ? v.z : v.w));
}

// ---------------------------------------------------------------------------
// numpy pairwise_sum emulation for n=128 contiguous f32 (AVX512 build):
// 8 vector accumulators of 16 lanes, combine ((r0+r1)+(r2+r3))+((r4+r5)+(r6+r7)),
// then _mm512_reduce_add_ps tree (stride 8,4, then (u0+u2)+(u1+u3)).
// ---------------------------------------------------------------------------
__device__ __forceinline__ float np_b128_sq(const float* p) {
    float L[16];
    #pragma unroll
    for (int l = 0; l < 16; ++l) {
        float y[8];
        #pragma unroll
        for (int j = 0; j < 8; ++j) { float v = p[j * 16 + l]; y[j] = __fmul_rn(v, v); }
        L[l] = __fadd_rn(__fadd_rn(__fadd_rn(y[0], y[1]), __fadd_rn(y[2], y[3])),
                         __fadd_rn(__fadd_rn(y[4], y[5]), __fadd_rn(y[6], y[7])));
    }
    float w[8];
    #pragma unroll
    for (int l = 0; l < 8; ++l) w[l] = __fadd_rn(L[l], L[l + 8]);
    float u[4];
    #pragma unroll
    for (int l = 0; l < 4; ++l) u[l] = __fadd_rn(w[l], w[l + 4]);
    return __fadd_rn(__fadd_rn(u[0], u[2]), __fadd_rn(u[1], u[3]));
}

__device__ __forceinline__ float np_b128_nsq(const float* p, float nrm) {
    float L[16];
    #pragma unroll
    for (int l = 0; l < 16; ++l) {
        float y[8];
        #pragma unroll
        for (int j = 0; j < 8; ++j) {
            float v = __fdiv_rn(p[j * 16 + l], nrm);
            y[j] = __fmul_rn(v, v);
        }
        L[l] = __fadd_rn(__fadd_rn(__fadd_rn(y[0], y[1]), __fadd_rn(y[2], y[3])),
                         __fadd_rn(__fadd_rn(y[4], y[5]), __fadd_rn(y[6], y[7])));
    }
    float w[8];
    #pragma unroll
    for (int l = 0; l < 8; ++l) w[l] = __fadd_rn(L[l], L[l + 8]);
    float u[4];
    #pragma unroll
    for (int l = 0; l < 4; ++l) u[l] = __fadd_rn(w[l], w[l + 4]);
    return __fadd_rn(__fadd_rn(u[0], u[2]), __fadd_rn(u[1], u[3]));
}

// ---------------------------------------------------------------------------
// Kernel 1: per-codebook-row: norm32 (np semantics), Ehat + EhatT, c32.
// grid 2 x 256. Also zeroes diff accumulator.
// ---------------------------------------------------------------------------
__global__ __launch_bounds__(256) void vq_prep(
    const float* __restrict__ EMB, float* __restrict__ Ehat,
    float* __restrict__ EhatT, float* __restrict__ c32,
    double* __restrict__ diff_sum)
{
    const int e = blockIdx.x * 256 + threadIdx.x;   // 0..511
    const float* row = EMB + e * 256;
    float ss  = __fadd_rn(np_b128_sq(row), np_b128_sq(row + 128));
    float nrm = __fsqrt_rn(ss);
    for (int d = 0; d < 256; ++d) {
        float eh = __fdiv_rn(row[d], nrm);
        Ehat[e * 256 + d]  = eh;
        EhatT[d * 512 + e] = eh;
    }
    c32[e] = __fadd_rn(np_b128_nsq(row, nrm), np_b128_nsq(row + 128, nrm));
    if (e == 0) *diff_sum = 0.0;
}

// ---------------------------------------------------------------------------
// Kernel 2: fused xx (np tree) + GEMM (sequential-k fp32 FMA chains, BLAS
// semantics) + np-exact dist + first-min argmin + gather/out + diff.
// grid 2048 x 256; block = 64 rows x 512 codes, j-tile 256 (2 jc chunks).
// Thread (tj=tid&15, tmG=tid>>4): rows tmG*4+[0..3], j = jc*256+pp*64+tj*4+c.
// ---------------------------------------------------------------------------
__global__ __launch_bounds__(256) void vq_main(
    const float* __restrict__ X, const float* __restrict__ EhatT,
    const float* __restrict__ Ehat, const float* __restrict__ C32,
    float* __restrict__ out, float* __restrict__ ind_out,
    double* __restrict__ diff_sum)
{
    __shared__ float4 ET4[32 * 64];     // 32 k-rows x 256 j (32 KB), k-major
    __shared__ int    indsh[64];
    __shared__ double dred[4];

    const int tid = threadIdx.x;
    const int tj  = tid & 15;
    const int tmG = tid >> 4;
    const int m0  = blockIdx.x * 64;

    const float4* xr0 = (const float4*)(X + (size_t)(m0 + tmG * 4 + 0) * 256);
    const float4* xr1 = (const float4*)(X + (size_t)(m0 + tmG * 4 + 1) * 256);
    const float4* xr2 = (const float4*)(X + (size_t)(m0 + tmG * 4 + 2) * 256);
    const float4* xr3 = (const float4*)(X + (size_t)(m0 + tmG * 4 + 3) * 256);
    const float4* Ev  = (const float4*)EhatT;

    // ---- fused xx: np pairwise tree per row, 16 lanes (tj) per row ----
    // lane tj holds AVX512 lane l=tj; butterfly 8/4/2/1 == the exact reduce
    // tree (pairwise fp adds are commutative, so all lanes get the bit-exact
    // tree value).
    float xxv[4];
    #pragma unroll
    for (int i = 0; i < 4; ++i) {
        const float* row = X + (size_t)(m0 + tmG * 4 + i) * 256;
        float y0[8], y1[8];
        #pragma unroll
        for (int j = 0; j < 8; ++j) {
            float v0 = row[j * 16 + tj];
            float v1 = row[128 + j * 16 + tj];
            y0[j] = __fmul_rn(v0, v0);
            y1[j] = __fmul_rn(v1, v1);
        }
        float L0 = __fadd_rn(__fadd_rn(__fadd_rn(y0[0], y0[1]), __fadd_rn(y0[2], y0[3])),
                             __fadd_rn(__fadd_rn(y0[4], y0[5]), __fadd_rn(y0[6], y0[7])));
        float L1 = __fadd_rn(__fadd_rn(__fadd_rn(y1[0], y1[1]), __fadd_rn(y1[2], y1[3])),
                             __fadd_rn(__fadd_rn(y1[4], y1[5]), __fadd_rn(y1[6], y1[7])));
        #pragma unroll
        for (int off = 8; off >= 1; off >>= 1) {
            L0 = __fadd_rn(L0, __shfl_xor(L0, off, 64));
            L1 = __fadd_rn(L1, __shfl_xor(L1, off, 64));
        }
        xxv[i] = __fadd_rn(L0, L1);
    }

    float bd[4]; int bj[4];
    #pragma unroll
    for (int i = 0; i < 4; ++i) { bd[i] = 3.0e38f; bj[i] = 0; }

    for (int jc = 0; jc < 2; ++jc) {
        float acc[4][16];
        #pragma unroll
        for (int i = 0; i < 4; ++i)
            #pragma unroll
            for (int c = 0; c < 16; ++c) acc[i][c] = 0.0f;

        for (int kc = 0; kc < 8; ++kc) {
            __syncthreads();
            #pragma unroll
            for (int p = 0; p < 8; ++p) {
                int L  = p * 256 + tid;       // 2048 float4 in tile
                int kk = L >> 6;              // 0..31
                int j4 = L & 63;
                ET4[kk * 64 + j4] = Ev[(size_t)(kc * 32 + kk) * 128 + jc * 64 + j4];
            }
            __syncthreads();
            // d = kc*32 + k4*4 + c4 ascends: each acc[i][*] is ONE sequential
            // fp32 FMA chain over d=0..255 from 0 (BLAS sgemm rank-1 order).
            #pragma unroll
            for (int k4 = 0; k4 < 8; ++k4) {
                const int f4i = kc * 8 + k4;
                float4 a0 = xr0[f4i];
                float4 a1 = xr1[f4i];
                float4 a2 = xr2[f4i];
                float4 a3 = xr3[f4i];
                #pragma unroll
                for (int c4 = 0; c4 < 4; ++c4) {
                    const int kb = (k4 * 4 + c4) * 64;
                    float4 b0 = ET4[kb + tj];
                    float4 b1 = ET4[kb + 16 + tj];
                    float4 b2 = ET4[kb + 32 + tj];
                    float4 b3 = ET4[kb + 48 + tj];
                    float av;
                    av = f4c(a0, c4);
                    acc[0][0]  = fmaf(av, b0.x, acc[0][0]);
                    acc[0][1]  = fmaf(av, b0.y, acc[0][1]);
                    acc[0][2]  = fmaf(av, b0.z, acc[0][2]);
                    acc[0][3]  = fmaf(av, b0.w, acc[0][3]);
                    acc[0][4]  = fmaf(av, b1.x, acc[0][4]);
                    acc[0][5]  = fmaf(av, b1.y, acc[0][5]);
                    acc[0][6]  = fmaf(av, b1.z, acc[0][6]);
                    acc[0][7]  = fmaf(av, b1.w, acc[0][7]);
                    acc[0][8]  = fmaf(av, b2.x, acc[0][8]);
                    acc[0][9]  = fmaf(av, b2.y, acc[0][9]);
                    acc[0][10] = fmaf(av, b2.z, acc[0][10]);
                    acc[0][11] = fmaf(av, b2.w, acc[0][11]);
                    acc[0][12] = fmaf(av, b3.x, acc[0][12]);
                    acc[0][13] = fmaf(av, b3.y, acc[0][13]);
                    acc[0][14] = fmaf(av, b3.z, acc[0][14]);
                    acc[0][15] = fmaf(av, b3.w, acc[0][15]);
                    av = f4c(a1, c4);
                    acc[1][0]  = fmaf(av, b0.x, acc[1][0]);
                    acc[1][1]  = fmaf(av, b0.y, acc[1][1]);
                    acc[1][2]  = fmaf(av, b0.z, acc[1][2]);
                    acc[1][3]  = fmaf(av, b0.w, acc[1][3]);
                    acc[1][4]  = fmaf(av, b1.x, acc[1][4]);
                    acc[1][5]  = fmaf(av, b1.y, acc[1][5]);
                    acc[1][6]  = fmaf(av, b1.z, acc[1][6]);
                    acc[1][7]  = fmaf(av, b1.w, acc[1][7]);
                    acc[1][8]  = fmaf(av, b2.x, acc[1][8]);
                    acc[1][9]  = fmaf(av, b2.y, acc[1][9]);
                    acc[1][10] = fmaf(av, b2.z, acc[1][10]);
                    acc[1][11] = fmaf(av, b2.w, acc[1][11]);
                    acc[1][12] = fmaf(av, b3.x, acc[1][12]);
                    acc[1][13] = fmaf(av, b3.y, acc[1][13]);
                    acc[1][14] = fmaf(av, b3.z, acc[1][14]);
                    acc[1][15] = fmaf(av, b3.w, acc[1][15]);
                    av = f4c(a2, c4);
                    acc[2][0]  = fmaf(av, b0.x, acc[2][0]);
                    acc[2][1]  = fmaf(av, b0.y, acc[2][1]);
                    acc[2][2]  = fmaf(av, b0.z, acc[2][2]);
                    acc[2][3]  = fmaf(av, b0.w, acc[2][3]);
                    acc[2][4]  = fmaf(av, b1.x, acc[2][4]);
                    acc[2][5]  = fmaf(av, b1.y, acc[2][5]);
                    acc[2][6]  = fmaf(av, b1.z, acc[2][6]);
                    acc[2][7]  = fmaf(av, b1.w, acc[2][7]);
                    acc[2][8]  = fmaf(av, b2.x, acc[2][8]);
                    acc[2][9]  = fmaf(av, b2.y, acc[2][9]);
                    acc[2][10] = fmaf(av, b2.z, acc[2][10]);
                    acc[2][11] = fmaf(av, b2.w, acc[2][11]);
                    acc[2][12] = fmaf(av, b3.x, acc[2][12]);
                    acc[2][13] = fmaf(av, b3.y, acc[2][13]);
                    acc[2][14] = fmaf(av, b3.z, acc[2][14]);
                    acc[2][15] = fmaf(av, b3.w, acc[2][15]);
                    av = f4c(a3, c4);
                    acc[3][0]  = fmaf(av, b0.x, acc[3][0]);
                    acc[3][1]  = fmaf(av, b0.y, acc[3][1]);
                    acc[3][2]  = fmaf(av, b0.z, acc[3][2]);
                    acc[3][3]  = fmaf(av, b0.w, acc[3][3]);
                    acc[3][4]  = fmaf(av, b1.x, acc[3][4]);
                    acc[3][5]  = fmaf(av, b1.y, acc[3][5]);
                    acc[3][6]  = fmaf(av, b1.z, acc[3][6]);
                    acc[3][7]  = fmaf(av, b1.w, acc[3][7]);
                    acc[3][8]  = fmaf(av, b2.x, acc[3][8]);
                    acc[3][9]  = fmaf(av, b2.y, acc[3][9]);
                    acc[3][10] = fmaf(av, b2.z, acc[3][10]);
                    acc[3][11] = fmaf(av, b2.w, acc[3][11]);
                    acc[3][12] = fmaf(av, b3.x, acc[3][12]);
                    acc[3][13] = fmaf(av, b3.y, acc[3][13]);
                    acc[3][14] = fmaf(av, b3.z, acc[3][14]);
                    acc[3][15] = fmaf(av, b3.w, acc[3][15]);
                }
            }
        }
        // np-exact dist32 = fl32( fl32(xx - 2g) + c_j ); argmin, first-min ties
        const float4* C4 = (const float4*)C32;
        #pragma unroll
        for (int pp = 0; pp < 4; ++pp) {
            float4 cjv = C4[jc * 64 + pp * 16 + tj];
            #pragma unroll
            for (int i = 0; i < 4; ++i)
                #pragma unroll
                for (int c = 0; c < 4; ++c) {
                    float g2  = __fmul_rn(2.0f, acc[i][pp * 4 + c]);
                    float d32 = __fadd_rn(__fsub_rn(xxv[i], g2), f4c(cjv, c));
                    int   j   = jc * 256 + pp * 64 + tj * 4 + c;   // ascending
                    if (d32 < bd[i]) { bd[i] = d32; bj[i] = j; }
                }
        }
    }

    // merge across the 16 tj lanes: min dist, ties -> smaller index
    #pragma unroll
    for (int off = 1; off <= 8; off <<= 1) {
        #pragma unroll
        for (int i = 0; i < 4; ++i) {
            float od = __shfl_xor(bd[i], off, 64);
            int   oj = __shfl_xor(bj[i], off, 64);
            if (od < bd[i] || (od == bd[i] && oj < bj[i])) { bd[i] = od; bj[i] = oj; }
        }
    }
    if (tj == 0) {
        #pragma unroll
        for (int i = 0; i < 4; ++i) indsh[tmG * 4 + i] = bj[i];
    }

    // diff: sum of min dists (loss is lax-graded; avoids re-reading X)
    double dacc = (tj == 0)
        ? ((double)bd[0] + (double)bd[1] + (double)bd[2] + (double)bd[3]) : 0.0;
    dacc += __shfl_xor(dacc, 32, 64);
    dacc += __shfl_xor(dacc, 16, 64);
    if ((tid & 63) == 0) dred[tid >> 6] = dacc;
    __syncthreads();
    if (tid == 0) atomicAdd(diff_sum, dred[0] + dred[1] + dred[2] + dred[3]);

    // epilogue: gather + float4 out-store (no X read)
    const float4* Eh4 = (const float4*)Ehat;
    float4* out4 = (float4*)out;
    const int cc = tid & 63;
    #pragma unroll
    for (int rr = 0; rr < 64; rr += 4) {
        int row = rr + (tid >> 6);
        int idx = indsh[row];
        out4[(size_t)(m0 + row) * 64 + cc] = Eh4[(size_t)idx * 64 + cc];
    }
    if (tid < 64) ind_out[m0 + tid] = (float)indsh[tid];
}

// ---------------------------------------------------------------------------
// Kernel 3: entropy + loss. 1 block x 256.
// ---------------------------------------------------------------------------
__global__ __launch_bounds__(256) void vq_ent_fin(
    const float* __restrict__ Ehat, const float* __restrict__ c32,
    const double* __restrict__ diff_sum, float* __restrict__ loss_out)
{
    __shared__ double red[256];
    const int tid = threadIdx.x;
    double sd = 0.0;
    for (int e = 0; e < 512; ++e) sd += (double)Ehat[e * 256 + tid];
    red[tid] = sd * sd;
    __syncthreads();
    for (int st = 128; st; st >>= 1) {
        if (tid < st) red[tid] += red[tid + st];
        __syncthreads();
    }
    double s2 = red[0];
    __syncthreads();
    red[tid] = (double)c32[tid] + (double)c32[tid + 256];
    __syncthreads();
    for (int st = 128; st; st >>= 1) {
        if (tid < st) red[tid] += red[tid + st];
        __syncthreads();
    }
    if (tid == 0) {
        double ent = 2.0 * 512.0 * red[0] - 2.0 * s2;
        *loss_out = (float)((*diff_sum) * (1.0 / (double)OUT_N)
                            - ent * (1.0 / (512.0 * 512.0)));
    }
}

// ---------------------------------------------------------------------------
extern "C" void kernel_launch(void* const* d_in, const int* in_sizes, int n_in,
                              void* d_out, int out_size, void* d_ws, size_t ws_size,
                              hipStream_t stream)
{
    const float* X   = (const float*)d_in[0];   // [32,4096,256] fp32
    const float* EMB = (const float*)d_in[1];   // [512,256] fp32

    float* out      = (float*)d_out;            // [N,D]
    float* loss_out = out + OUT_N;              // scalar
    float* ind_out  = out + OUT_N + 1;          // [N] (float-encoded indices)

    char* ws = (char*)d_ws;
    double* diff_sum = (double*)(ws + WS_DIFF);
    float*  c32      = (float*) (ws + C32_OFF);
    float*  Ehat     = (float*) (ws + EHAT_OFF);
    float*  EhatT    = (float*) (ws + EHATT_OFF);

    vq_prep<<<2, 256, 0, stream>>>(EMB, Ehat, EhatT, c32, diff_sum);
    vq_main<<<2048, 256, 0, stream>>>(X, EhatT, Ehat, c32, out, ind_out, diff_sum);
    vq_ent_fin<<<1, 256, 0, stream>>>(Ehat, c32, diff_sum, loss_out);
}